// Round 3
// baseline (1396.862 us; speedup 1.0000x reference)
//
#include <hip/hip_runtime.h>
#include <stdint.h>

#define T_STEPS 512
#define F_IN 30
#define HID 32
#define ROWS 16   // batch rows per wave (one MFMA M-tile); 1 wave per block

typedef __attribute__((ext_vector_type(8))) short short8;   // 8 bf16 (4 VGPRs)
typedef __attribute__((ext_vector_type(4))) float floatx4;  // 4 f32 acc

#define MFMA(a, b, c) __builtin_amdgcn_mfma_f32_16x16x32_bf16((a), (b), (c), 0, 0, 0)

__device__ __forceinline__ unsigned short f2bf(float f) {
    uint32_t u = __float_as_uint(f);
    u += 0x7fffu + ((u >> 16) & 1u);            // RTNE
    return (unsigned short)(u >> 16);
}
__device__ __forceinline__ float bf2f(unsigned short h) {
    return __uint_as_float(((uint32_t)h) << 16);
}
__device__ __forceinline__ uint32_t pack_hl(float f) {
    unsigned short hi = f2bf(f);
    unsigned short lo = f2bf(f - bf2f(hi));      // exact residual split
    return (uint32_t)hi | ((uint32_t)lo << 16);
}
__device__ __forceinline__ float sigm(float x)      { return 1.0f / (1.0f + __expf(-x)); }
__device__ __forceinline__ float tanh_fast(float x) { return 1.0f - 2.0f / (1.0f + __expf(2.0f * x)); }

__device__ __forceinline__ void loadx8(float (&d)[8], const float* p, bool tail) {
    float2 a0 = *(const float2*)(p + 0);
    float2 a1 = *(const float2*)(p + 2);
    float2 a2 = *(const float2*)(p + 4);
    float2 a3 = make_float2(0.f, 0.f);
    if (!tail) a3 = *(const float2*)(p + 6);     // quad3 covers features 24..29 + zero pad
    d[0]=a0.x; d[1]=a0.y; d[2]=a1.x; d[3]=a1.y;
    d[4]=a2.x; d[5]=a2.y; d[6]=a3.x; d[7]=a3.y;
}

// One wave (64 threads) owns 16 batch rows end-to-end: all 128 gate columns
// as 8 MFMA n-tiles, activations, state update, h transpose, fused heads.
// ZERO barriers: the only cross-lane traffic is wave-private LDS + shuffles.
__global__ __launch_bounds__(64, 1)
void lstm_wave_kernel(const float* __restrict__ x, const float* __restrict__ h0,
                      const float* __restrict__ c0, const float* __restrict__ W_ih,
                      const float* __restrict__ W_hh, const float* __restrict__ b_ih,
                      const float* __restrict__ b_hh, const float* __restrict__ W_all,
                      const float* __restrict__ b_all, const float* __restrict__ W_pos,
                      const float* __restrict__ b_pos, const float* __restrict__ W_lv,
                      const float* __restrict__ b_lv, float* __restrict__ pos_out,
                      float* __restrict__ lv_out, float* __restrict__ hT_out,
                      float* __restrict__ cT_out)
{
    const int tid  = threadIdx.x;     // 0..63, one wave
    const int quad = tid >> 4;
    const int l15  = tid & 15;
    const int rowbase = blockIdx.x * ROWS;

    __shared__ __align__(16) uint32_t hbuf[ROWS][36];   // packed hi|lo bf16 h, stride 36 (2-way max)

    // ---- B-fragments for all 8 n-tiles: B[k=quad*8+j][n=tile*16+l15], hi/lo split ----
    short8 wxh[8], wxl[8], whh_[8], whl_[8];
    float bias[8];
#pragma unroll
    for (int tl = 0; tl < 8; ++tl) {
        const int gcol = tl * 16 + l15;
        short8 xh, xl, hh, hl;
#pragma unroll
        for (int j = 0; j < 8; ++j) {
            const int k = quad * 8 + j;
            float wx = (k < F_IN) ? W_ih[gcol * F_IN + k] : 0.0f;
            unsigned short h1 = f2bf(wx);
            xh[j] = (short)h1; xl[j] = (short)f2bf(wx - bf2f(h1));
            float wh = W_hh[gcol * HID + k];
            unsigned short h2 = f2bf(wh);
            hh[j] = (short)h2; hl[j] = (short)f2bf(wh - bf2f(h2));
        }
        wxh[tl] = xh; wxl[tl] = xl; whh_[tl] = hh; whl_[tl] = hl;
        bias[tl] = b_ih[gcol] + b_hh[gcol];
    }

    // ---- folded head weights for units quad*8+j (head lane role: row l15) ----
    float wc0[8] = {0,0,0,0,0,0,0,0}, wc1[8] = {0,0,0,0,0,0,0,0}, wlv8[8];
    float bc0 = b_pos[0], bc1 = b_pos[1];
    {
        float s0 = 0.f, s1 = 0.f;
#pragma unroll 4
        for (int o = 0; o < HID; ++o) {
            const float wp0 = W_pos[o], wp1 = W_pos[HID + o];
            s0 += wp0 * b_all[o]; s1 += wp1 * b_all[o];
#pragma unroll
            for (int j = 0; j < 8; ++j) {
                const float wa = W_all[o * HID + quad * 8 + j];
                wc0[j] += wp0 * wa; wc1[j] += wp1 * wa;
            }
        }
        bc0 += s0; bc1 += s1;
    }
#pragma unroll
    for (int j = 0; j < 8; ++j) wlv8[j] = W_lv[quad * 8 + j];
    const float blv = b_lv[0];

    // ---- state: lane owns (rows quad*4+r, units {l15, l15+16}) ----
    float cst[4][2], hst[4][2];
#pragma unroll
    for (int r = 0; r < 4; ++r)
#pragma unroll
        for (int hf = 0; hf < 2; ++hf) {
            const int urow = rowbase + quad * 4 + r;
            const int unit = l15 + 16 * hf;
            cst[r][hf] = c0[(size_t)urow * HID + unit];
            hst[r][hf] = h0[(size_t)urow * HID + unit];
            hbuf[quad * 4 + r][unit] = pack_hl(hst[r][hf]);
        }

    // ---- pointers ----
    const float* xlane = x + (size_t)(rowbase + l15) * T_STEPS * F_IN + quad * 8;
    const bool tail = (quad == 3);
    const float* mbase = x + (size_t)rowbase * T_STEPS * F_IN + (F_IN - 1);
    const float* mup[4];
#pragma unroll
    for (int r = 0; r < 4; ++r) mup[r] = mbase + (size_t)(quad * 4 + r) * T_STEPS * F_IN;
    const float* mhead = mbase + (size_t)l15 * T_STEPS * F_IN;

    // depth-4 register prefetch ring (x fragment + update masks + head mask)
    float xr[4][8]; float mu[4][4]; float mh[4];
    auto pre = [&](int slot, int tp) {
        loadx8(xr[slot], xlane + tp * F_IN, tail);
#pragma unroll
        for (int r = 0; r < 4; ++r) mu[slot][r] = mup[r][tp * F_IN];
        mh[slot] = mhead[tp * F_IN];
    };
    pre(0, 0); pre(1, 1); pre(2, 2); pre(3, 3);
    float mh_prev = 0.f;

    auto step = [&](int t, int slot) {
        // h A-fragment read (h_{t-1}, written end of previous step; in-order DS pipe)
        uint32_t hw[8];
        *(uint4*)&hw[0] = *(const uint4*)&hbuf[l15][quad * 8];
        *(uint4*)&hw[4] = *(const uint4*)&hbuf[l15][quad * 8 + 4];
        // x fragment convert (prefetched 4 steps ago)
        short8 xah;
#pragma unroll
        for (int j = 0; j < 8; ++j) xah[j] = (short)f2bf(xr[slot][j]);
        float mck[4];
#pragma unroll
        for (int r = 0; r < 4; ++r) mck[r] = mu[slot][r];
        const float mhp = mh_prev;          // mask[t-1] for head row l15
        mh_prev = mh[slot];                 // mask[t]
        // prefetch t+4 into this ring slot
        const int tp = (t + 4 < T_STEPS) ? t + 4 : (T_STEPS - 1);
        pre(slot, tp);

        short8 hah, hal;
#pragma unroll
        for (int j = 0; j < 8; ++j) {
            hah[j] = (short)(hw[j] & 0xffffu);
            hal[j] = (short)(hw[j] >> 16);
        }
        // 40 MFMAs: 8 independent acc chains of depth 5
        floatx4 acc[8];
#pragma unroll
        for (int tl = 0; tl < 8; ++tl) { floatx4 b = {bias[tl], bias[tl], bias[tl], bias[tl]}; acc[tl] = b; }
#pragma unroll
        for (int tl = 0; tl < 8; ++tl) acc[tl] = MFMA(xah, wxh[tl], acc[tl]);
#pragma unroll
        for (int tl = 0; tl < 8; ++tl) acc[tl] = MFMA(xah, wxl[tl], acc[tl]);
#pragma unroll
        for (int tl = 0; tl < 8; ++tl) acc[tl] = MFMA(hah, whh_[tl], acc[tl]);
#pragma unroll
        for (int tl = 0; tl < 8; ++tl) acc[tl] = MFMA(hal, whh_[tl], acc[tl]);
#pragma unroll
        for (int tl = 0; tl < 8; ++tl) acc[tl] = MFMA(hah, whl_[tl], acc[tl]);

        // heads for step t-1 from transposed h (out = mask * h_st identity)
        {
            float hfv[8];
#pragma unroll
            for (int j = 0; j < 8; ++j) hfv[j] = bf2f((unsigned short)hah[j]);
            float p0 = 0.f, p1 = 0.f, pl = 0.f;
#pragma unroll
            for (int j = 0; j < 8; ++j) {
                p0 = fmaf(wc0[j], hfv[j], p0);
                p1 = fmaf(wc1[j], hfv[j], p1);
                pl = fmaf(wlv8[j], hfv[j], pl);
            }
            p0 += __shfl_xor(p0, 16); p1 += __shfl_xor(p1, 16); pl += __shfl_xor(pl, 16);
            p0 += __shfl_xor(p0, 32); p1 += __shfl_xor(p1, 32); pl += __shfl_xor(pl, 32);
            if (t > 0 && quad == 0) {
                const size_t o = (size_t)(rowbase + l15) * T_STEPS + (t - 1);
                *(float2*)&pos_out[o * 2] = make_float2(fmaf(mhp, p0, bc0), fmaf(mhp, p1, bc1));
                lv_out[o] = sigm(fmaf(mhp, pl, blv));
            }
        }

        // activations + update + h transpose write (no cross-lane needed)
#pragma unroll
        for (int r = 0; r < 4; ++r) {
            const bool on = (mck[r] == 1.0f);
#pragma unroll
            for (int hf = 0; hf < 2; ++hf) {
                const float gi = sigm(acc[0 + hf][r]);
                const float gf = sigm(acc[2 + hf][r]);
                const float gg = tanh_fast(acc[4 + hf][r]);
                const float go = sigm(acc[6 + hf][r]);
                const float cn = gf * cst[r][hf] + gi * gg;
                const float hn = go * tanh_fast(cn);
                if (on) { cst[r][hf] = cn; hst[r][hf] = hn; }
                hbuf[quad * 4 + r][l15 + 16 * hf] = pack_hl(hst[r][hf]);
            }
        }
    };

    for (int t = 0; t < T_STEPS; t += 4) {
        step(t + 0, 0);
        step(t + 1, 1);
        step(t + 2, 2);
        step(t + 3, 3);
    }

    // final heads (t = T-1) from the last transposed h
    {
        uint32_t hw[8];
        *(uint4*)&hw[0] = *(const uint4*)&hbuf[l15][quad * 8];
        *(uint4*)&hw[4] = *(const uint4*)&hbuf[l15][quad * 8 + 4];
        float p0 = 0.f, p1 = 0.f, pl = 0.f;
#pragma unroll
        for (int j = 0; j < 8; ++j) {
            const float hfv = bf2f((unsigned short)(hw[j] & 0xffffu));
            p0 = fmaf(wc0[j], hfv, p0);
            p1 = fmaf(wc1[j], hfv, p1);
            pl = fmaf(wlv8[j], hfv, pl);
        }
        p0 += __shfl_xor(p0, 16); p1 += __shfl_xor(p1, 16); pl += __shfl_xor(pl, 16);
        p0 += __shfl_xor(p0, 32); p1 += __shfl_xor(p1, 32); pl += __shfl_xor(pl, 32);
        if (quad == 0) {
            const size_t o = (size_t)(rowbase + l15) * T_STEPS + (T_STEPS - 1);
            *(float2*)&pos_out[o * 2] = make_float2(fmaf(mh_prev, p0, bc0), fmaf(mh_prev, p1, bc1));
            lv_out[o] = sigm(fmaf(mh_prev, pl, blv));
        }
    }

    // final states
#pragma unroll
    for (int r = 0; r < 4; ++r)
#pragma unroll
        for (int hf = 0; hf < 2; ++hf) {
            const int urow = rowbase + quad * 4 + r;
            const int unit = l15 + 16 * hf;
            hT_out[(size_t)urow * HID + unit] = hst[r][hf];
            cT_out[(size_t)urow * HID + unit] = cst[r][hf];
        }
}

extern "C" void kernel_launch(void* const* d_in, const int* in_sizes, int n_in,
                              void* d_out, int out_size, void* d_ws, size_t ws_size,
                              hipStream_t stream) {
    const float* x     = (const float*)d_in[0];
    const float* h0    = (const float*)d_in[1];
    const float* c0    = (const float*)d_in[2];
    const float* W_ih  = (const float*)d_in[3];
    const float* W_hh  = (const float*)d_in[4];
    const float* b_ih  = (const float*)d_in[5];
    const float* b_hh  = (const float*)d_in[6];
    const float* W_all = (const float*)d_in[7];
    const float* b_all = (const float*)d_in[8];
    const float* W_pos = (const float*)d_in[9];
    const float* b_pos = (const float*)d_in[10];
    const float* W_lv  = (const float*)d_in[11];
    const float* b_lv  = (const float*)d_in[12];

    const int B = in_sizes[1] / HID;         // h0 is [1,B,H] -> 4096
    float* out     = (float*)d_out;
    float* pos_out = out;                                    // [B,T,2]
    float* lv_out  = pos_out + (size_t)B * T_STEPS * 2;      // [B,T,1]
    float* hT_out  = lv_out  + (size_t)B * T_STEPS;          // [1,B,H]
    float* cT_out  = hT_out  + (size_t)B * HID;              // [1,B,H]

    dim3 grid(B / ROWS), block(64);
    hipLaunchKernelGGL(lstm_wave_kernel, grid, block, 0, stream,
                       x, h0, c0, W_ih, W_hh, b_ih, b_hh, W_all, b_all,
                       W_pos, b_pos, W_lv, b_lv, pos_out, lv_out, hT_out, cT_out);
}

// Round 4
// 1310.207 us; speedup vs baseline: 1.0661x; 1.0661x over previous
//
#include <hip/hip_runtime.h>
#include <stdint.h>

#define T_STEPS 512
#define F_IN 30
#define HID 32
#define ROWS 16   // batch rows per block (one MFMA M-tile)

typedef __attribute__((ext_vector_type(8))) short short8;   // 8 bf16 (4 VGPRs)
typedef __attribute__((ext_vector_type(4))) float floatx4;  // 4 f32 acc

#define MFMA(a, b, c) __builtin_amdgcn_mfma_f32_16x16x32_bf16((a), (b), (c), 0, 0, 0)

// Raw barrier: drain LDS only; global prefetch loads ride across.
#define BAR() asm volatile("s_waitcnt lgkmcnt(0)\n\ts_barrier" ::: "memory")

__device__ __forceinline__ unsigned short f2bf(float f) {
    uint32_t u = __float_as_uint(f);
    u += 0x7fffu + ((u >> 16) & 1u);            // RTNE
    return (unsigned short)(u >> 16);
}
__device__ __forceinline__ float bf2f(unsigned short h) {
    return __uint_as_float(((uint32_t)h) << 16);
}
__device__ __forceinline__ float sigm(float x)      { return 1.0f / (1.0f + __expf(-x)); }
__device__ __forceinline__ float tanh_fast(float x) { return 1.0f - 2.0f / (1.0f + __expf(2.0f * x)); }

__device__ __forceinline__ void loadx8(float (&d)[8], const float* p, bool tail) {
    float2 a0 = *(const float2*)(p + 0);
    float2 a1 = *(const float2*)(p + 2);
    float2 a2 = *(const float2*)(p + 4);
    float2 a3 = make_float2(0.f, 0.f);
    if (!tail) a3 = *(const float2*)(p + 6);     // quad3: feats 24..29 + zero pad
    d[0]=a0.x; d[1]=a0.y; d[2]=a1.x; d[3]=a1.y;
    d[4]=a2.x; d[5]=a2.y; d[6]=a3.x; d[7]=a3.y;
}

// 4 waves per block, one 16-row tile. Wave w computes gate-type w via MFMA,
// activates it (4-way trans split), exchanges activated gates through LDS
// (ONE raw barrier, double-buffered). Every wave then REDUNDANTLY updates the
// cell slice matching its next A-fragment (row=l15, units=quad*8..+7), so h
// stays in registers — no transpose, no second barrier. Head duty rotates.
__global__ __launch_bounds__(256, 1)
void lstm_x4_kernel(const float* __restrict__ x, const float* __restrict__ h0,
                    const float* __restrict__ c0, const float* __restrict__ W_ih,
                    const float* __restrict__ W_hh, const float* __restrict__ b_ih,
                    const float* __restrict__ b_hh, const float* __restrict__ W_all,
                    const float* __restrict__ b_all, const float* __restrict__ W_pos,
                    const float* __restrict__ b_pos, const float* __restrict__ W_lv,
                    const float* __restrict__ b_lv, float* __restrict__ pos_out,
                    float* __restrict__ lv_out, float* __restrict__ hT_out,
                    float* __restrict__ cT_out)
{
    const int tid  = threadIdx.x;
    const int wv   = tid >> 6;        // wave 0..3 == gate type i/f/g/o
    const int quad = (tid & 63) >> 4;
    const int l15  = tid & 15;
    const int rowbase = blockIdx.x * ROWS;

    // double-buffered activated-gate exchange; stride 132 (16B-aligned, banks balanced)
    __shared__ float gbuf[2][ROWS][132];

    // ---- weight B-fragments: this wave's 2 n-tiles (gatecols wv*32 .. wv*32+31) ----
    short8 wxh[2], wxl[2], whh2[2], whl2[2];
    float biasc[2];
#pragma unroll
    for (int tl = 0; tl < 2; ++tl) {
        const int gcol = (wv * 2 + tl) * 16 + l15;
        short8 xh, xl, hh, hl;
#pragma unroll
        for (int j = 0; j < 8; ++j) {
            const int k = quad * 8 + j;
            float wx = (k < F_IN) ? W_ih[gcol * F_IN + k] : 0.0f;
            unsigned short h1 = f2bf(wx);
            xh[j] = (short)h1; xl[j] = (short)f2bf(wx - bf2f(h1));
            float wh = W_hh[gcol * HID + k];
            unsigned short h2 = f2bf(wh);
            hh[j] = (short)h2; hl[j] = (short)f2bf(wh - bf2f(h2));
        }
        wxh[tl] = xh; wxl[tl] = xl; whh2[tl] = hh; whl2[tl] = hl;
        biasc[tl] = b_ih[gcol] + b_hh[gcol];
    }

    // ---- cell slice: row srow = rowbase+l15, units quad*8 .. quad*8+7 ----
    const int srow = rowbase + l15;
    float c8[8], h8[8];
    {
        float4 a = *(const float4*)&c0[(size_t)srow * HID + quad * 8];
        float4 b = *(const float4*)&c0[(size_t)srow * HID + quad * 8 + 4];
        c8[0]=a.x; c8[1]=a.y; c8[2]=a.z; c8[3]=a.w;
        c8[4]=b.x; c8[5]=b.y; c8[6]=b.z; c8[7]=b.w;
        float4 e = *(const float4*)&h0[(size_t)srow * HID + quad * 8];
        float4 f = *(const float4*)&h0[(size_t)srow * HID + quad * 8 + 4];
        h8[0]=e.x; h8[1]=e.y; h8[2]=e.z; h8[3]=e.w;
        h8[4]=f.x; h8[5]=f.y; h8[6]=f.z; h8[7]=f.w;
    }
    short8 hah, hal;
#pragma unroll
    for (int j = 0; j < 8; ++j) {
        unsigned short hi = f2bf(h8[j]);
        hah[j] = (short)hi; hal[j] = (short)f2bf(h8[j] - bf2f(hi));
    }

    // ---- folded head weights for units quad*8+j (all waves; duty rotates) ----
    float wc0[8] = {0,0,0,0,0,0,0,0}, wc1[8] = {0,0,0,0,0,0,0,0}, wlv8[8];
    float bc0 = b_pos[0], bc1 = b_pos[1];
    {
        float s0 = 0.f, s1 = 0.f;
#pragma unroll 4
        for (int o = 0; o < HID; ++o) {
            const float wp0 = W_pos[o], wp1 = W_pos[HID + o];
            s0 += wp0 * b_all[o]; s1 += wp1 * b_all[o];
#pragma unroll
            for (int j = 0; j < 8; ++j) {
                const float wa = W_all[o * HID + quad * 8 + j];
                wc0[j] += wp0 * wa; wc1[j] += wp1 * wa;
            }
        }
        bc0 += s0; bc1 += s1;
    }
#pragma unroll
    for (int j = 0; j < 8; ++j) wlv8[j] = W_lv[quad * 8 + j];
    const float blv = b_lv[0];

    // ---- x fragment + mask pointers (both row srow) ----
    const float* xlane = x + (size_t)srow * T_STEPS * F_IN + quad * 8;
    const float* mptr  = x + (size_t)srow * T_STEPS * F_IN + (F_IN - 1);
    const bool tail = (quad == 3);

    float xr[4][8]; float mk[4];
#pragma unroll
    for (int s = 0; s < 4; ++s) { loadx8(xr[s], xlane + s * F_IN, tail); mk[s] = mptr[s * F_IN]; }

    const bool isg = (wv == 2);

    auto step = [&](int t, int slot) {
        const float mcur = mk[slot];
        short8 xah;
#pragma unroll
        for (int j = 0; j < 8; ++j) xah[j] = (short)f2bf(xr[slot][j]);
        {   // prefetch t+4 into this ring slot (rides across raw barriers)
            const int tp = (t + 4 < T_STEPS) ? t + 4 : (T_STEPS - 1);
            loadx8(xr[slot], xlane + tp * F_IN, tail);
            mk[slot] = mptr[tp * F_IN];
        }
        // two shallow MFMA chain pairs per tile (depth 3 + depth 2)
        floatx4 aA0 = {biasc[0], biasc[0], biasc[0], biasc[0]};
        floatx4 aA1 = {biasc[1], biasc[1], biasc[1], biasc[1]};
        floatx4 aB0 = {0.f, 0.f, 0.f, 0.f}, aB1 = {0.f, 0.f, 0.f, 0.f};
        aA0 = MFMA(xah, wxh[0], aA0);   aA1 = MFMA(xah, wxh[1], aA1);
        aB0 = MFMA(xah, wxl[0], aB0);   aB1 = MFMA(xah, wxl[1], aB1);
        aA0 = MFMA(hah, whh2[0], aA0);  aA1 = MFMA(hah, whh2[1], aA1);
        aB0 = MFMA(hah, whl2[0], aB0);  aB1 = MFMA(hah, whl2[1], aB1);
        aA0 = MFMA(hal, whh2[0], aA0);  aA1 = MFMA(hal, whh2[1], aA1);

        const int p = t & 1;
        // own-type activation (C-layout: row=quad*4+r, col=wv*32+l15(+16))
#pragma unroll
        for (int r = 0; r < 4; ++r) {
            float a0 = aA0[r] + aB0[r];
            float a1 = aA1[r] + aB1[r];
            a0 = isg ? tanh_fast(a0) : sigm(a0);
            a1 = isg ? tanh_fast(a1) : sigm(a1);
            gbuf[p][quad * 4 + r][wv * 32 + l15]      = a0;
            gbuf[p][quad * 4 + r][wv * 32 + 16 + l15] = a1;
        }
        BAR();
        // gather all 4 gate types for my cell slice (16B-aligned float4s)
        float gi[8], gf[8], gg[8], go[8];
        *(float4*)&gi[0] = *(const float4*)&gbuf[p][l15][  0 + quad * 8];
        *(float4*)&gi[4] = *(const float4*)&gbuf[p][l15][  4 + quad * 8];
        *(float4*)&gf[0] = *(const float4*)&gbuf[p][l15][ 32 + quad * 8];
        *(float4*)&gf[4] = *(const float4*)&gbuf[p][l15][ 36 + quad * 8];
        *(float4*)&gg[0] = *(const float4*)&gbuf[p][l15][ 64 + quad * 8];
        *(float4*)&gg[4] = *(const float4*)&gbuf[p][l15][ 68 + quad * 8];
        *(float4*)&go[0] = *(const float4*)&gbuf[p][l15][ 96 + quad * 8];
        *(float4*)&go[4] = *(const float4*)&gbuf[p][l15][100 + quad * 8];

        const bool on = (mcur == 1.0f);
        float out8[8];
#pragma unroll
        for (int j = 0; j < 8; ++j) {
            const float cn = gf[j] * c8[j] + gi[j] * gg[j];
            const float hn = go[j] * tanh_fast(cn);
            if (on) { c8[j] = cn; h8[j] = hn; }
            out8[j] = on ? hn : 0.0f;
        }
        // rebuild next A-fragment in-register (no LDS transpose)
#pragma unroll
        for (int j = 0; j < 8; ++j) {
            unsigned short hi = f2bf(h8[j]);
            hah[j] = (short)hi; hal[j] = (short)f2bf(h8[j] - bf2f(hi));
        }
        // heads: duty wave for this step (all waves hold identical out8)
        if (wv == (t & 3)) {
            float p0 = 0.f, p1 = 0.f, pl = 0.f;
#pragma unroll
            for (int j = 0; j < 8; ++j) {
                p0 = fmaf(wc0[j], out8[j], p0);
                p1 = fmaf(wc1[j], out8[j], p1);
                pl = fmaf(wlv8[j], out8[j], pl);
            }
            p0 += __shfl_xor(p0, 16); p1 += __shfl_xor(p1, 16); pl += __shfl_xor(pl, 16);
            p0 += __shfl_xor(p0, 32); p1 += __shfl_xor(p1, 32); pl += __shfl_xor(pl, 32);
            if (quad == 0) {
                const size_t o = (size_t)srow * T_STEPS + t;
                *(float2*)&pos_out[o * 2] = make_float2(p0 + bc0, p1 + bc1);
                lv_out[o] = sigm(pl + blv);
            }
        }
    };

    for (int t = 0; t < T_STEPS; t += 4) {
        step(t + 0, 0);
        step(t + 1, 1);
        step(t + 2, 2);
        step(t + 3, 3);
    }

    // final states (all waves identical; wave 1 stores)
    if (wv == 1) {
        float4 a, b;
        a.x=h8[0]; a.y=h8[1]; a.z=h8[2]; a.w=h8[3];
        b.x=h8[4]; b.y=h8[5]; b.z=h8[6]; b.w=h8[7];
        *(float4*)&hT_out[(size_t)srow * HID + quad * 8]     = a;
        *(float4*)&hT_out[(size_t)srow * HID + quad * 8 + 4] = b;
        a.x=c8[0]; a.y=c8[1]; a.z=c8[2]; a.w=c8[3];
        b.x=c8[4]; b.y=c8[5]; b.z=c8[6]; b.w=c8[7];
        *(float4*)&cT_out[(size_t)srow * HID + quad * 8]     = a;
        *(float4*)&cT_out[(size_t)srow * HID + quad * 8 + 4] = b;
    }
}

extern "C" void kernel_launch(void* const* d_in, const int* in_sizes, int n_in,
                              void* d_out, int out_size, void* d_ws, size_t ws_size,
                              hipStream_t stream) {
    const float* x     = (const float*)d_in[0];
    const float* h0    = (const float*)d_in[1];
    const float* c0    = (const float*)d_in[2];
    const float* W_ih  = (const float*)d_in[3];
    const float* W_hh  = (const float*)d_in[4];
    const float* b_ih  = (const float*)d_in[5];
    const float* b_hh  = (const float*)d_in[6];
    const float* W_all = (const float*)d_in[7];
    const float* b_all = (const float*)d_in[8];
    const float* W_pos = (const float*)d_in[9];
    const float* b_pos = (const float*)d_in[10];
    const float* W_lv  = (const float*)d_in[11];
    const float* b_lv  = (const float*)d_in[12];

    const int B = in_sizes[1] / HID;         // h0 is [1,B,H] -> 4096
    float* out     = (float*)d_out;
    float* pos_out = out;                                    // [B,T,2]
    float* lv_out  = pos_out + (size_t)B * T_STEPS * 2;      // [B,T,1]
    float* hT_out  = lv_out  + (size_t)B * T_STEPS;          // [1,B,H]
    float* cT_out  = hT_out  + (size_t)B * HID;              // [1,B,H]

    dim3 grid(B / ROWS), block(256);
    hipLaunchKernelGGL(lstm_x4_kernel, grid, block, 0, stream,
                       x, h0, c0, W_ih, W_hh, b_ih, b_hh, W_all, b_all,
                       W_pos, b_pos, W_lv, b_lv, pos_out, lv_out, hT_out, cT_out);
}